// Round 4
// baseline (916.317 us; speedup 1.0000x reference)
//
#include <hip/hip_runtime.h>
#include <stdint.h>

#define NB 4
#define NC 512
#define NH 64
#define NW 96
#define NA 9
#define NPIX (NB*NA*NH*NW)   // 221184
#define KSEL 2048
#define NOUT 50
#define THRS 0.05f

#define HIST_BASE 0x3D4CCu   // bits(0.05f)>>12
#define HIST_SIZE 9024
#define CAND_CAP 8192

typedef _Float16 half8 __attribute__((ext_vector_type(8)));
typedef float floatx16 __attribute__((ext_vector_type(16)));

__device__ const float ANC_W[9] = {128.f,128.f,256.f,256.f,256.f,512.f,512.f,512.f,1024.f};
__device__ const float ANC_H[9] = {128.f,256.f,128.f,256.f,512.f,256.f,512.f,1024.f,512.f};

// ============ weight expand (coalesced, LDS transpose) ============
// w1[co][ci][3][3] fp32 -> wexp2[(cc*9+kk)][kd(4)][co(512)] half8 (16B units)
// kd = kind*2 + khalf; kind0 = hi, kind1 = lo; values pre-scaled by 1024.
__global__ __launch_bounds__(256) void wexp2_k(const float* __restrict__ w1,
                                               uint4* __restrict__ wexp2) {
    __shared__ __align__(16) _Float16 lbuf[36 * 32 * 8];   // 18432 B
    const int bid = blockIdx.x;
    const int cc = bid >> 4, cog = bid & 15;
    const int t = threadIdx.x;
    const int co_l = t >> 3, j = t & 7;
    const int co = cog * 32 + co_l;
    const float* r0 = w1 + ((size_t)co * 512 + cc * 16 + j) * 9;      // ci = cc*16+j
    const float* r1 = r0 + 8 * 9;                                      // ci = cc*16+8+j
#pragma unroll
    for (int kk = 0; kk < 9; ++kk) {
        const float v0 = r0[kk] * 1024.f;
        const float v1 = r1[kk] * 1024.f;
        const _Float16 h0 = (_Float16)v0, h1 = (_Float16)v1;
        const _Float16 l0 = (_Float16)(v0 - (float)h0);
        const _Float16 l1 = (_Float16)(v1 - (float)h1);
        lbuf[((kk * 4 + 0) * 32 + co_l) * 8 + j] = h0;
        lbuf[((kk * 4 + 1) * 32 + co_l) * 8 + j] = h1;
        lbuf[((kk * 4 + 2) * 32 + co_l) * 8 + j] = l0;
        lbuf[((kk * 4 + 3) * 32 + co_l) * 8 + j] = l1;
    }
    __syncthreads();
    for (int e = t; e < 1152; e += 256) {
        const int co_e = e & 31;
        const int rest = e >> 5;            // kk*4 + kd (0..35)
        const int kk = rest >> 2, kd = rest & 3;
        const uint4 v = *(const uint4*)&lbuf[(rest * 32 + co_e) * 8];
        wexp2[(((size_t)(cc * 9 + kk) * 4 + kd) * 512) + cog * 32 + co_e] = v;
    }
}

// ============ conv3x3 via fp16 MFMA, 3-term split ============
// grid 512: bid&3 = co-quarter (128 co), bid>>2 = px-block (b, 8 rows x 24 cols)
// block 256 thr = 4 waves: (hpx 2) x (nh 2); wave tile 96 px (3 mt) x 64 co (2 nt)
// kg = 3 chunks (one ky row); 2 barriers per kg; 2 blocks/CU for cross-block overlap.
#define XS_BYTES 20800           // 260 slots * 80 B
#define WB_BYTES 24576           // 3 chunks * 4 planes * 128 co * 16 B
#define CONV_LDS (XS_BYTES + WB_BYTES)

__global__ __launch_bounds__(256, 2) void conv_mfma(
    const float* __restrict__ x, const uint4* __restrict__ wexp2,
    const float* __restrict__ b1, float* __restrict__ f)
{
    __shared__ __align__(16) char smem[CONV_LDS];
    char* xs = smem;
    char* wb = smem + XS_BYTES;
    const int t = threadIdx.x;
    const int bid = blockIdx.x;
    const int qco = bid & 3, pxb = bid >> 2;
    const int b = pxb >> 5, r = pxb & 31, by = r >> 2, bx = r & 3;
    const int y0 = by * 8, x0 = bx * 24;
    const int wv = t >> 6, lane = t & 63;
    const int hpx = wv >> 1, nh = wv & 1;
    const int m32 = lane & 31, khalf = lane >> 5;

    int abase[3];
#pragma unroll
    for (int mt = 0; mt < 3; ++mt) {
        const int px = hpx * 96 + mt * 32 + m32;
        const int yl = px / 24, xl = px - yl * 24;
        abase[mt] = (yl * 26 + xl) * 80 + khalf * 16;
    }
    const int bb0 = khalf * 2048 + (nh * 64 + m32) * 16;   // + c3*8192, + nt*512, + kind*4096

    floatx16 acc[3][2];
#pragma unroll
    for (int mt = 0; mt < 3; ++mt)
#pragma unroll
        for (int nt = 0; nt < 2; ++nt)
#pragma unroll
            for (int i = 0; i < 16; ++i) acc[mt][nt][i] = 0.f;

    // weight prefetch: thread covers (kd=pp, co_l) and (kd=pp+2, co_l) for 3 chunks
    const int co_l = t & 127, pp = t >> 7;
    const uint4* wsrc = wexp2 + qco * 128 + co_l;
    uint4 pf[3][2];
    auto loadw3 = [&](int g2) {
#pragma unroll
        for (int c3 = 0; c3 < 3; ++c3) {
            const size_t base = (size_t)(3 * g2 + c3) * 2048;
            pf[c3][0] = wsrc[base + (size_t)pp * 512];
            pf[c3][1] = wsrc[base + (size_t)(pp + 2) * 512];
        }
    };
    const int wa0 = pp * 2048 + co_l * 16;
    const int wa1 = (pp + 2) * 2048 + co_l * 16;

    const float* xb = x + (size_t)b * NC * (NH * NW);
    auto stage_x = [&](int cc) {
        const float* xc = xb + (size_t)cc * 16 * (NH * NW);
        for (int it = t; it < 520; it += 256) {
            const int kh = (it >= 260) ? 1 : 0;
            const int slot = it - kh * 260;
            const int ya = slot / 26, xa = slot - ya * 26;
            const int gy = y0 - 1 + ya, gx = x0 - 1 + xa;
            const bool ok = (gy >= 0 && gy < NH && gx >= 0 && gx < NW);
            const int off = ok ? (kh * 8 * 6144 + gy * 96 + gx) : 0;
            union { _Float16 h[8]; uint4 u; } hi, lo;
#pragma unroll
            for (int j = 0; j < 8; ++j) {
                const float v = (ok ? xc[off + j * 6144] : 0.f) * 1024.f;
                const _Float16 hh = (_Float16)v;
                hi.h[j] = hh;
                lo.h[j] = (_Float16)(v - (float)hh);
            }
            *(uint4*)(xs + slot * 80 + kh * 16) = hi.u;
            *(uint4*)(xs + slot * 80 + 32 + kh * 16) = lo.u;
        }
    };

    loadw3(0);
    stage_x(0);

    for (int g = 0; g < 96; ++g) {
        const int ky = g % 3, cc = g / 3;
        __syncthreads();                     // compute g-1 done; prefetched loads drained
        // commit weights for kg g (loaded during g-1)
#pragma unroll
        for (int c3 = 0; c3 < 3; ++c3) {
            *(uint4*)(wb + c3 * 8192 + wa0) = pf[c3][0];
            *(uint4*)(wb + c3 * 8192 + wa1) = pf[c3][1];
        }
        if (ky == 0 && g > 0) stage_x(cc);
        __syncthreads();                     // wb + xs visible
        if (g < 95) loadw3(g + 1);           // window = compute of kg g
        // ---- compute 3 chunks ----
#pragma unroll
        for (int c3 = 0; c3 < 3; ++c3) {
            const char* xcur = xs + (ky * 26 + c3) * 80;
            half8 axh[3], axl[3];
#pragma unroll
            for (int mt = 0; mt < 3; ++mt) {
                axh[mt] = *(const half8*)(xcur + abase[mt]);
                axl[mt] = *(const half8*)(xcur + abase[mt] + 32);
            }
            const char* wc = wb + c3 * 8192 + bb0;
            half8 bwh[2], bwl[2];
#pragma unroll
            for (int nt = 0; nt < 2; ++nt) {
                bwh[nt] = *(const half8*)(wc + nt * 512);
                bwl[nt] = *(const half8*)(wc + 4096 + nt * 512);
            }
#pragma unroll
            for (int nt = 0; nt < 2; ++nt)
#pragma unroll
                for (int mt = 0; mt < 3; ++mt)
                    acc[mt][nt] = __builtin_amdgcn_mfma_f32_32x32x16_f16(
                        axh[mt], bwh[nt], acc[mt][nt], 0, 0, 0);
#pragma unroll
            for (int nt = 0; nt < 2; ++nt)
#pragma unroll
                for (int mt = 0; mt < 3; ++mt)
                    acc[mt][nt] = __builtin_amdgcn_mfma_f32_32x32x16_f16(
                        axh[mt], bwl[nt], acc[mt][nt], 0, 0, 0);
#pragma unroll
            for (int nt = 0; nt < 2; ++nt)
#pragma unroll
                for (int mt = 0; mt < 3; ++mt)
                    acc[mt][nt] = __builtin_amdgcn_mfma_f32_32x32x16_f16(
                        axl[mt], bwh[nt], acc[mt][nt], 0, 0, 0);
        }
    }

    // epilogue: descale 2^-20, + bias, store f[px][co]
    const float inv = 1.0f / 1048576.0f;
#pragma unroll
    for (int mt = 0; mt < 3; ++mt)
#pragma unroll
        for (int nt = 0; nt < 2; ++nt) {
            const int co = qco * 128 + nh * 64 + nt * 32 + m32;
            const float bias = b1[co];
#pragma unroll
            for (int reg = 0; reg < 16; ++reg) {
                const int row = (reg & 3) + 8 * (reg >> 2) + 4 * khalf;
                const int pxl = hpx * 96 + mt * 32 + row;
                const int yl = pxl / 24, xl = pxl - yl * 24;
                const size_t gpx = (size_t)(b * 64 + y0 + yl) * 96 + (x0 + xl);
                f[gpx * 512 + co] = acc[mt][nt][reg] * inv + bias;
            }
        }
}

// ============ fused heads + softmax: f[24576][512] -> scores, regs ============
// grid 192, block 256: px_l = t&127 (128 px/block), oh = t>>7 (27 oc each)
__global__ __launch_bounds__(256) void head_k(
    const float* __restrict__ f, const float* __restrict__ wcls,
    const float* __restrict__ wreg, const float* __restrict__ bcls,
    const float* __restrict__ breg, float* __restrict__ scores,
    float* __restrict__ regs)
{
    __shared__ __align__(16) float smem[6912 + 128 * 57];   // 56.0 KB
    float* wls = smem;                 // [54][128]
    float* lt  = smem + 6912;          // [128][57]
    const int t = threadIdx.x;
    const int px0 = blockIdx.x * 128;
    const int px_l = t & 127, oh = t >> 7;
    float acc27[27];
#pragma unroll
    for (int k = 0; k < 27; ++k) acc27[k] = 0.f;

    for (int qd = 0; qd < 4; ++qd) {
        __syncthreads();
        for (int e = t; e < 6912; e += 256) {
            const int oc = e >> 7, c = e & 127;
            wls[e] = (oc < 18) ? wcls[oc * 512 + qd * 128 + c]
                               : wreg[(oc - 18) * 512 + qd * 128 + c];
        }
        __syncthreads();
        const float4* fp = (const float4*)(f + (size_t)(px0 + px_l) * 512 + qd * 128);
        const float4* wp4 = (const float4*)wls;
#pragma unroll 4
        for (int c4 = 0; c4 < 32; ++c4) {
            const float4 fv = fp[c4];
#pragma unroll
            for (int k = 0; k < 27; ++k) {
                const float4 wv = wp4[(oh * 27 + k) * 32 + c4];
                acc27[k] += fv.x * wv.x + fv.y * wv.y + fv.z * wv.z + fv.w * wv.w;
            }
        }
    }
    __syncthreads();
#pragma unroll
    for (int k = 0; k < 27; ++k) lt[px_l * 57 + oh * 27 + k] = acc27[k];
    __syncthreads();

    if (t < 128) {
        const int px = px0 + t;
        const float* row = lt + t * 57;
        float cl[18];
        float m = -1e30f;
#pragma unroll
        for (int oc = 0; oc < 18; ++oc) {
            cl[oc] = row[oc] + bcls[oc];
            m = fmaxf(m, cl[oc]);
        }
        float sum = 0.f;
#pragma unroll
        for (int oc = 0; oc < 18; ++oc) { cl[oc] = expf(cl[oc] - m); sum += cl[oc]; }
        const float inv = 1.f / sum;
        const int b = px / 6144;
        const int yx = px - b * 6144;
#pragma unroll
        for (int a = 0; a < 9; ++a) {
            const int idx = b * 55296 + a * 6144 + yx;
            scores[idx] = cl[2 * a + 1] * inv;
            float4 rv;
            rv.x = row[18 + a * 4 + 0] + breg[a * 4 + 0];
            rv.y = row[18 + a * 4 + 1] + breg[a * 4 + 1];
            rv.z = row[18 + a * 4 + 2] + breg[a * 4 + 2];
            rv.w = row[18 + a * 4 + 3] + breg[a * 4 + 3];
            ((float4*)regs)[idx] = rv;
        }
    }
}

// ---------------- histogram over score float bits ----------------
__global__ void hist_k(const float* __restrict__ scores, uint32_t* __restrict__ hist) {
    const int i = blockIdx.x * 256 + threadIdx.x;
    const float s = scores[i];
    if (s >= THRS) {
        int bkt = (int)(__float_as_uint(s) >> 12) - (int)HIST_BASE;
        bkt = min(max(bkt, 0), HIST_SIZE - 1);
        atomicAdd(&hist[bkt], 1u);
    }
}

// ---------------- suffix scan -> cutoff bucket ----------------
__global__ void scan_k(const uint32_t* __restrict__ hist, uint32_t* __restrict__ ctl) {
    __shared__ uint32_t ssum[1024];
    const int t = threadIdx.x;
    uint32_t s = 0;
#pragma unroll
    for (int u = 0; u < 9; ++u) {
        const int bkt = t * 9 + u;
        if (bkt < HIST_SIZE) s += hist[bkt];
    }
    const uint32_t mysum = s;
    ssum[t] = s;
    __syncthreads();
    for (int off = 1; off < 1024; off <<= 1) {
        uint32_t v = (t + off < 1024) ? ssum[t + off] : 0u;
        __syncthreads();
        ssum[t] += v;
        __syncthreads();
    }
    const uint32_t total = ssum[0];
    const uint32_t above = (t < 1023) ? ssum[t + 1] : 0u;
    if (total < KSEL) {
        if (t == 0) ctl[0] = HIST_BASE;
    } else if (above < KSEL && above + mysum >= KSEL) {
        uint32_t run = above;
        for (int u = 8; u >= 0; --u) {
            const int bkt = t * 9 + u;
            if (bkt >= HIST_SIZE) continue;
            run += hist[bkt];
            if (run >= KSEL) { ctl[0] = HIST_BASE + (uint32_t)bkt; break; }
        }
    }
}

// ---------------- compact candidates above cutoff ----------------
__global__ void collect_k(const float* __restrict__ scores, uint32_t* __restrict__ ctl,
                          uint64_t* __restrict__ cand) {
    const int i = blockIdx.x * 256 + threadIdx.x;
    const float s = scores[i];
    if (s >= THRS) {
        const uint32_t bits = __float_as_uint(s);
        if ((bits >> 12) >= ctl[0]) {
            const uint32_t pos = atomicAdd(&ctl[1], 1u);
            if (pos < CAND_CAP)
                cand[pos] = ((uint64_t)bits << 32) | (uint64_t)(0xFFFFFFFFu - (uint32_t)i);
        }
    }
}

// ---------------- single-block bitonic sort (desc) + box decode ----------------
__global__ void sort_decode_k(const uint64_t* __restrict__ cand, const uint32_t* __restrict__ ctl,
                              const float* __restrict__ regs,
                              const int* __restrict__ hp, const int* __restrict__ wp,
                              float* __restrict__ tops_s, float* __restrict__ boxes) {
    __shared__ uint64_t keys[CAND_CAP];
    const int t = threadIdx.x;
    const int M = min((int)ctl[1], CAND_CAP);
    const int N = (M <= 4096) ? 4096 : 8192;
    for (int k = t; k < N; k += 1024) keys[k] = (k < M) ? cand[k] : 0ull;
    __syncthreads();
    for (int size = 2; size <= N; size <<= 1) {
        for (int stride = size >> 1; stride > 0; stride >>= 1) {
            for (int k = t; k < N; k += 1024) {
                const int p = k ^ stride;
                if (p > k) {
                    const uint64_t a = keys[k], bb = keys[p];
                    const bool sw = ((k & size) == 0) ? (a < bb) : (a > bb);
                    if (sw) { keys[k] = bb; keys[p] = a; }
                }
            }
            __syncthreads();
        }
    }
    const int w_in = wp[0], h_in = hp[0];
    const float offx = (float)((w_in - 16) % 16) * 0.5f + 8.0f;
    const float offy = (float)((h_in - 16) % 16) * 0.5f + 8.0f;
    for (int k = t; k < KSEL; k += 1024) {
        const uint64_t key = keys[k];
        float sc = -1.f, x1 = 0.f, y1 = 0.f, x2 = 0.f, y2 = 0.f;
        if (k < M && key != 0ull) {
            const uint32_t idx = 0xFFFFFFFFu - (uint32_t)(key & 0xFFFFFFFFull);
            sc = __uint_as_float((uint32_t)(key >> 32));
            const int a  = (int)(idx / (NH * NW)) % NA;
            const int yy = (int)(idx / NW) % NH;
            const int xx = (int)(idx % NW);
            const float4 r = ((const float4*)regs)[idx];
            const float aw = ANC_W[a], ah = ANC_H[a];
            const float cx = (float)xx * 16.f + offx;
            const float cy = (float)yy * 16.f + offy;
            const float bx = r.x * aw + cx;
            const float by = r.y * ah + cy;
            const float bw = expf(r.z) * aw;
            const float bh = expf(r.w) * ah;
            x1 = bx - bw * 0.5f; y1 = by - bh * 0.5f;
            x2 = bx + bw * 0.5f; y2 = by + bh * 0.5f;
        }
        tops_s[k] = sc;
        ((float4*)boxes)[k] = make_float4(x1, y1, x2, y2);
    }
}

// ---------------- pairwise IoU suppression bitmask ----------------
__global__ void iou_k(const float* __restrict__ boxes, uint64_t* __restrict__ mask) {
    __shared__ float4 jb[64];
    const int t = threadIdx.x;
    const int bi = blockIdx.x, bj = blockIdx.y;
    jb[t] = ((const float4*)boxes)[bj * 64 + t];
    __syncthreads();
    const int i = bi * 64 + t;
    const float4 mb = ((const float4*)boxes)[i];
    const float areai = (mb.z - mb.x) * (mb.w - mb.y);
    uint64_t w = 0;
    for (int jj = 0; jj < 64; ++jj) {
        const float4 ob = jb[jj];
        const int j = bj * 64 + jj;
        const float ix1 = fmaxf(mb.x, ob.x);
        const float iy1 = fmaxf(mb.y, ob.y);
        const float ix2 = fminf(mb.z, ob.z);
        const float iy2 = fminf(mb.w, ob.w);
        const float inter = fmaxf(ix2 - ix1, 0.f) * fmaxf(iy2 - iy1, 0.f);
        const float areaj = (ob.z - ob.x) * (ob.w - ob.y);
        const float iou = inter / (areai + areaj - inter + 1e-9f);
        if (iou > 0.7f && j > i) w |= (1ull << jj);
    }
    mask[(size_t)i * 32 + bj] = w;
}

// ---------------- sequential greedy NMS (single wave, early exit, prefetch) ----------------
__global__ void nms_k(const float* __restrict__ tops_s, const float* __restrict__ boxes,
                      const uint64_t* __restrict__ mask, float* __restrict__ out) {
    __shared__ uint64_t remv[32];
    __shared__ float ssc[KSEL];
    __shared__ int sel[NOUT];
    const int t = threadIdx.x;      // 64 threads = 1 wave
    for (int k = t; k < KSEL; k += 64) ssc[k] = tops_s[k];
    if (t < 32) remv[t] = 0ull;
    uint64_t nextrow = (t < 32) ? mask[t] : 0ull;   // row 0 prefetch
    int cnt = 0;                    // wave-uniform
    for (int i = 0; i < KSEL && cnt < NOUT; ++i) {
        const uint64_t cur = nextrow;
        if (t < 32 && i + 1 < KSEL) nextrow = mask[(size_t)(i + 1) * 32 + t];
        const uint64_t rw = remv[i >> 6];
        const bool sup = (rw >> (i & 63)) & 1ull;
        if (ssc[i] >= THRS && !sup) {
            if (t < 32) remv[t] |= cur;
            if (t == 0) sel[cnt] = i;
            ++cnt;
        }
    }
    for (int k = t; k < NOUT; k += 64) {
        float s = 0.f;
        float4 bb = make_float4(0.f, 0.f, 0.f, 0.f);
        if (k < cnt) { const int i = sel[k]; s = ssc[i]; bb = ((const float4*)boxes)[i]; }
        out[k] = s;
        out[NOUT + k * 4 + 0] = bb.x;
        out[NOUT + k * 4 + 1] = bb.y;
        out[NOUT + k * 4 + 2] = bb.z;
        out[NOUT + k * 4 + 3] = bb.w;
    }
}

extern "C" void kernel_launch(void* const* d_in, const int* in_sizes, int n_in,
                              void* d_out, int out_size, void* d_ws, size_t ws_size,
                              hipStream_t stream) {
    const float* x    = (const float*)d_in[0];
    const float* w1   = (const float*)d_in[1];
    const float* b1   = (const float*)d_in[2];
    const float* wcls = (const float*)d_in[3];
    const float* bcls = (const float*)d_in[4];
    const float* wreg = (const float*)d_in[5];
    const float* breg = (const float*)d_in[6];
    const int*   hp   = (const int*)d_in[7];
    const int*   wp   = (const int*)d_in[8];
    float* out = (float*)d_out;

    char* ws = (char*)d_ws;
    size_t off = 0;
    auto carve = [&](size_t bytes) -> void* {
        void* p = ws + off;
        off = (off + bytes + 255) & ~(size_t)255;
        return p;
    };
    uint4*    wexp2  = (uint4*)carve((size_t)288 * 4 * 512 * 16);      // 9.44 MB
    float*    f      = (float*)carve((size_t)24576 * 512 * 4);         // 50.3 MB
    float*    scores = (float*)carve((size_t)NPIX * 4);
    float*    regs   = (float*)carve((size_t)NPIX * 16);
    uint32_t* hist   = (uint32_t*)carve((size_t)HIST_SIZE * 4);
    uint32_t* ctl    = (uint32_t*)carve(256);
    uint64_t* cand   = (uint64_t*)carve((size_t)CAND_CAP * 8);
    float*    tops_s = (float*)carve((size_t)KSEL * 4);
    float*    boxes  = (float*)carve((size_t)KSEL * 16);
    uint64_t* mask   = (uint64_t*)carve((size_t)KSEL * 32 * 8);
    (void)ws_size; (void)in_sizes; (void)n_in; (void)out_size;

    hipMemsetAsync(hist, 0, (size_t)HIST_SIZE * 4, stream);
    hipMemsetAsync(ctl, 0, 256, stream);

    wexp2_k<<<512, 256, 0, stream>>>(w1, wexp2);
    conv_mfma<<<512, 256, 0, stream>>>(x, wexp2, b1, f);
    head_k<<<192, 256, 0, stream>>>(f, wcls, wreg, bcls, breg, scores, regs);
    hist_k<<<NPIX / 256, 256, 0, stream>>>(scores, hist);
    scan_k<<<1, 1024, 0, stream>>>(hist, ctl);
    collect_k<<<NPIX / 256, 256, 0, stream>>>(scores, ctl, cand);
    sort_decode_k<<<1, 1024, 0, stream>>>(cand, ctl, regs, hp, wp, tops_s, boxes);
    iou_k<<<dim3(KSEL / 64, KSEL / 64), 64, 0, stream>>>(boxes, mask);
    nms_k<<<1, 64, 0, stream>>>(tops_s, boxes, mask, out);
}

// Round 5
// 668.284 us; speedup vs baseline: 1.3711x; 1.3711x over previous
//
#include <hip/hip_runtime.h>
#include <stdint.h>

#define NB 4
#define NC 512
#define NH 64
#define NW 96
#define NA 9
#define NPIX (NB*NA*NH*NW)   // 221184
#define KSEL 2048
#define NOUT 50
#define THRS 0.05f

#define HIST_BASE 0x3D4CCu   // bits(0.05f)>>12
#define HIST_SIZE 9024
#define CAND_CAP 8192

typedef _Float16 half8 __attribute__((ext_vector_type(8)));
typedef float floatx16 __attribute__((ext_vector_type(16)));

__device__ const float ANC_W[9] = {128.f,128.f,256.f,256.f,256.f,512.f,512.f,512.f,1024.f};
__device__ const float ANC_H[9] = {128.f,256.f,128.f,256.f,512.f,256.f,512.f,1024.f,512.f};

// ============ weight expand (coalesced, LDS transpose) ============
// w1[co][ci][3][3] fp32 -> wexp2[(cc*9+kk)][kd(4)][co(512)] half8 (16B units)
// kd = kind*2 + khalf; kind0 = hi, kind1 = lo; values pre-scaled by 1024.
__global__ __launch_bounds__(256) void wexp2_k(const float* __restrict__ w1,
                                               uint4* __restrict__ wexp2) {
    __shared__ __align__(16) _Float16 lbuf[36 * 32 * 8];   // 18432 B
    const int bid = blockIdx.x;
    const int cc = bid >> 4, cog = bid & 15;
    const int t = threadIdx.x;
    const int co_l = t >> 3, j = t & 7;
    const int co = cog * 32 + co_l;
    const float* r0 = w1 + ((size_t)co * 512 + cc * 16 + j) * 9;      // ci = cc*16+j
    const float* r1 = r0 + 8 * 9;                                      // ci = cc*16+8+j
#pragma unroll
    for (int kk = 0; kk < 9; ++kk) {
        const float v0 = r0[kk] * 1024.f;
        const float v1 = r1[kk] * 1024.f;
        const _Float16 h0 = (_Float16)v0, h1 = (_Float16)v1;
        const _Float16 l0 = (_Float16)(v0 - (float)h0);
        const _Float16 l1 = (_Float16)(v1 - (float)h1);
        lbuf[((kk * 4 + 0) * 32 + co_l) * 8 + j] = h0;
        lbuf[((kk * 4 + 1) * 32 + co_l) * 8 + j] = h1;
        lbuf[((kk * 4 + 2) * 32 + co_l) * 8 + j] = l0;
        lbuf[((kk * 4 + 3) * 32 + co_l) * 8 + j] = l1;
    }
    __syncthreads();
    for (int e = t; e < 1152; e += 256) {
        const int co_e = e & 31;
        const int rest = e >> 5;            // kk*4 + kd (0..35)
        const int kk = rest >> 2, kd = rest & 3;
        const uint4 v = *(const uint4*)&lbuf[(rest * 32 + co_e) * 8];
        wexp2[(((size_t)(cc * 9 + kk) * 4 + kd) * 512) + cog * 32 + co_e] = v;
    }
}

// ============ conv3x3 via fp16 MFMA, 3-term split ============
// grid 512: bid&1 = co-half (256 co), bid>>1 = px-tile (b, 4 rows x 24 cols = 96 px)
// block 512 thr = 8 waves: wave wq owns a 32-co slice; wave tile 96 px (3 mt) x 32 co
// 2 blocks/CU (launch_bounds(512,4)): independent blocks overlap barrier stalls.
// Write geometry = R2's clean co-half pattern (128-B wave segments, 2 writers/row).
#define XS_BYTES 12480           // 156 slots (6x26 halo) * 80 B
#define WB_BYTES 16384           // 4 planes * 256 co * 16 B (per chunk)
#define CONV_LDS (XS_BYTES + 2*WB_BYTES)

__global__ __launch_bounds__(512, 4) void conv_mfma(
    const float* __restrict__ x, const uint4* __restrict__ wexp2,
    const float* __restrict__ b1, float* __restrict__ f)
{
    __shared__ __align__(16) char smem[CONV_LDS];
    char* xs = smem;
    char* wb = smem + XS_BYTES;
    const int t = threadIdx.x;
    const int bid = blockIdx.x;
    const int half = bid & 1, pxb = bid >> 1;
    const int b = pxb >> 6, r = pxb & 63, by = r >> 2, bx = r & 3;
    const int y0 = by * 4, x0 = bx * 24;
    const int wq = t >> 6, lane = t & 63;
    const int m32 = lane & 31, khalf = lane >> 5;

    int abase[3];
#pragma unroll
    for (int mt = 0; mt < 3; ++mt) {
        const int px = mt * 32 + m32;
        const int yl = px / 24, xl = px - yl * 24;
        abase[mt] = (yl * 26 + xl) * 80 + khalf * 16;
    }
    const int bb0 = (wq * 32 + m32) * 16 + khalf * 4096;   // + kind*8192, + (q&1)*WB

    floatx16 acc[3];
#pragma unroll
    for (int mt = 0; mt < 3; ++mt)
#pragma unroll
        for (int i = 0; i < 16; ++i) acc[mt][i] = 0.f;

    // weight prefetch lanes: thread covers (kd=pp, co_l) and (kd=pp+2, co_l)
    const int co_l = t & 255, pp = t >> 8;
    const uint4* wsrc = wexp2 + half * 256 + co_l;
    uint4 pf0, pf1;
    auto loadw = [&](int q2) {
        const size_t base = (size_t)q2 * 2048;
        pf0 = wsrc[base + (size_t)pp * 512];
        pf1 = wsrc[base + (size_t)(pp + 2) * 512];
    };
    const int wa0 = pp * 4096 + co_l * 16;
    const int wa1 = (pp + 2) * 4096 + co_l * 16;

    const float* xb = x + (size_t)b * NC * (NH * NW);
    auto stage_x = [&](int cc) {
        const float* xc = xb + (size_t)cc * 16 * (NH * NW);
        for (int it = t; it < 312; it += 512) {
            const int kh = (it >= 156) ? 1 : 0;
            const int slot = it - kh * 156;
            const int ya = slot / 26, xa = slot - ya * 26;
            const int gy = y0 - 1 + ya, gx = x0 - 1 + xa;
            const bool ok = (gy >= 0 && gy < NH && gx >= 0 && gx < NW);
            const int off = ok ? (kh * 8 * 6144 + gy * 96 + gx) : 0;
            union { _Float16 h[8]; uint4 u; } hi, lo;
#pragma unroll
            for (int j = 0; j < 8; ++j) {
                const float v = (ok ? xc[off + j * 6144] : 0.f) * 1024.f;
                const _Float16 hh = (_Float16)v;
                hi.h[j] = hh;
                lo.h[j] = (_Float16)(v - (float)hh);
            }
            *(uint4*)(xs + slot * 80 + kh * 16) = hi.u;
            *(uint4*)(xs + slot * 80 + 32 + kh * 16) = lo.u;
        }
    };

    loadw(0);
    // pre-commit chunk 0 into buf 0 (no reader yet)
    *(uint4*)(wb + wa0) = pf0;
    *(uint4*)(wb + wa1) = pf1;
    loadw(1);

    int cc = 0, kk = 0;
    for (int q = 0; q < 288; ++q) {
        if (kk == 0) {
            __syncthreads();                 // prev-cc xs readers done
            stage_x(cc);
        }
        __syncthreads();                     // wb[q&1] + xs visible; wb[(q+1)&1] free
        if (q < 287) {
            char* wd = wb + ((q + 1) & 1) * WB_BYTES;
            *(uint4*)(wd + wa0) = pf0;       // commit chunk q+1
            *(uint4*)(wd + wa1) = pf1;
            if (q < 286) loadw(q + 2);       // prefetch chunk q+2 (full chunk to land)
        }
        // ---- compute chunk q: 9 MFMA (3 steps x 3 mt) ----
        {
            const int ky = kk / 3, kx = kk - ky * 3;
            const char* xcur = xs + (ky * 26 + kx) * 80;
            half8 axh[3], axl[3];
#pragma unroll
            for (int mt = 0; mt < 3; ++mt) {
                axh[mt] = *(const half8*)(xcur + abase[mt]);
                axl[mt] = *(const half8*)(xcur + abase[mt] + 32);
            }
            const char* wc = wb + (q & 1) * WB_BYTES + bb0;
            const half8 bwh = *(const half8*)(wc);
            const half8 bwl = *(const half8*)(wc + 8192);
#pragma unroll
            for (int mt = 0; mt < 3; ++mt)
                acc[mt] = __builtin_amdgcn_mfma_f32_32x32x16_f16(
                    axh[mt], bwh, acc[mt], 0, 0, 0);
#pragma unroll
            for (int mt = 0; mt < 3; ++mt)
                acc[mt] = __builtin_amdgcn_mfma_f32_32x32x16_f16(
                    axh[mt], bwl, acc[mt], 0, 0, 0);
#pragma unroll
            for (int mt = 0; mt < 3; ++mt)
                acc[mt] = __builtin_amdgcn_mfma_f32_32x32x16_f16(
                    axl[mt], bwh, acc[mt], 0, 0, 0);
        }
        if (++kk == 9) { kk = 0; ++cc; }
    }

    // epilogue: descale 2^-20, + bias, store f[px][co]  (R2-clean write geometry)
    const float inv = 1.0f / 1048576.0f;
    const int co = half * 256 + wq * 32 + m32;
    const float bias = b1[co];
#pragma unroll
    for (int mt = 0; mt < 3; ++mt) {
#pragma unroll
        for (int reg = 0; reg < 16; ++reg) {
            const int row = (reg & 3) + 8 * (reg >> 2) + 4 * khalf;
            const int pxl = mt * 32 + row;
            const int yl = pxl / 24, xl = pxl - yl * 24;
            const size_t gpx = (size_t)(b * 64 + y0 + yl) * 96 + (x0 + xl);
            f[gpx * 512 + co] = acc[mt][reg] * inv + bias;
        }
    }
}

// ============ fused heads + softmax: f[24576][512] -> scores, regs ============
// grid 192, block 256: px_l = t&127 (128 px/block), oh = t>>7 (27 oc each)
__global__ __launch_bounds__(256) void head_k(
    const float* __restrict__ f, const float* __restrict__ wcls,
    const float* __restrict__ wreg, const float* __restrict__ bcls,
    const float* __restrict__ breg, float* __restrict__ scores,
    float* __restrict__ regs)
{
    __shared__ __align__(16) float smem[6912 + 128 * 57];   // 56.0 KB
    float* wls = smem;                 // [54][128]
    float* lt  = smem + 6912;          // [128][57]
    const int t = threadIdx.x;
    const int px0 = blockIdx.x * 128;
    const int px_l = t & 127, oh = t >> 7;
    float acc27[27];
#pragma unroll
    for (int k = 0; k < 27; ++k) acc27[k] = 0.f;

    for (int qd = 0; qd < 4; ++qd) {
        __syncthreads();
        for (int e = t; e < 6912; e += 256) {
            const int oc = e >> 7, c = e & 127;
            wls[e] = (oc < 18) ? wcls[oc * 512 + qd * 128 + c]
                               : wreg[(oc - 18) * 512 + qd * 128 + c];
        }
        __syncthreads();
        const float4* fp = (const float4*)(f + (size_t)(px0 + px_l) * 512 + qd * 128);
        const float4* wp4 = (const float4*)wls;
#pragma unroll 4
        for (int c4 = 0; c4 < 32; ++c4) {
            const float4 fv = fp[c4];
#pragma unroll
            for (int k = 0; k < 27; ++k) {
                const float4 wv = wp4[(oh * 27 + k) * 32 + c4];
                acc27[k] += fv.x * wv.x + fv.y * wv.y + fv.z * wv.z + fv.w * wv.w;
            }
        }
    }
    __syncthreads();
#pragma unroll
    for (int k = 0; k < 27; ++k) lt[px_l * 57 + oh * 27 + k] = acc27[k];
    __syncthreads();

    if (t < 128) {
        const int px = px0 + t;
        const float* row = lt + t * 57;
        float cl[18];
        float m = -1e30f;
#pragma unroll
        for (int oc = 0; oc < 18; ++oc) {
            cl[oc] = row[oc] + bcls[oc];
            m = fmaxf(m, cl[oc]);
        }
        float sum = 0.f;
#pragma unroll
        for (int oc = 0; oc < 18; ++oc) { cl[oc] = expf(cl[oc] - m); sum += cl[oc]; }
        const float inv = 1.f / sum;
        const int b = px / 6144;
        const int yx = px - b * 6144;
#pragma unroll
        for (int a = 0; a < 9; ++a) {
            const int idx = b * 55296 + a * 6144 + yx;
            scores[idx] = cl[2 * a + 1] * inv;
            float4 rv;
            rv.x = row[18 + a * 4 + 0] + breg[a * 4 + 0];
            rv.y = row[18 + a * 4 + 1] + breg[a * 4 + 1];
            rv.z = row[18 + a * 4 + 2] + breg[a * 4 + 2];
            rv.w = row[18 + a * 4 + 3] + breg[a * 4 + 3];
            ((float4*)regs)[idx] = rv;
        }
    }
}

// ---------------- histogram over score float bits ----------------
__global__ void hist_k(const float* __restrict__ scores, uint32_t* __restrict__ hist) {
    const int i = blockIdx.x * 256 + threadIdx.x;
    const float s = scores[i];
    if (s >= THRS) {
        int bkt = (int)(__float_as_uint(s) >> 12) - (int)HIST_BASE;
        bkt = min(max(bkt, 0), HIST_SIZE - 1);
        atomicAdd(&hist[bkt], 1u);
    }
}

// ---------------- suffix scan -> cutoff bucket ----------------
__global__ void scan_k(const uint32_t* __restrict__ hist, uint32_t* __restrict__ ctl) {
    __shared__ uint32_t ssum[1024];
    const int t = threadIdx.x;
    uint32_t s = 0;
#pragma unroll
    for (int u = 0; u < 9; ++u) {
        const int bkt = t * 9 + u;
        if (bkt < HIST_SIZE) s += hist[bkt];
    }
    const uint32_t mysum = s;
    ssum[t] = s;
    __syncthreads();
    for (int off = 1; off < 1024; off <<= 1) {
        uint32_t v = (t + off < 1024) ? ssum[t + off] : 0u;
        __syncthreads();
        ssum[t] += v;
        __syncthreads();
    }
    const uint32_t total = ssum[0];
    const uint32_t above = (t < 1023) ? ssum[t + 1] : 0u;
    if (total < KSEL) {
        if (t == 0) ctl[0] = HIST_BASE;
    } else if (above < KSEL && above + mysum >= KSEL) {
        uint32_t run = above;
        for (int u = 8; u >= 0; --u) {
            const int bkt = t * 9 + u;
            if (bkt >= HIST_SIZE) continue;
            run += hist[bkt];
            if (run >= KSEL) { ctl[0] = HIST_BASE + (uint32_t)bkt; break; }
        }
    }
}

// ---------------- compact candidates above cutoff ----------------
__global__ void collect_k(const float* __restrict__ scores, uint32_t* __restrict__ ctl,
                          uint64_t* __restrict__ cand) {
    const int i = blockIdx.x * 256 + threadIdx.x;
    const float s = scores[i];
    if (s >= THRS) {
        const uint32_t bits = __float_as_uint(s);
        if ((bits >> 12) >= ctl[0]) {
            const uint32_t pos = atomicAdd(&ctl[1], 1u);
            if (pos < CAND_CAP)
                cand[pos] = ((uint64_t)bits << 32) | (uint64_t)(0xFFFFFFFFu - (uint32_t)i);
        }
    }
}

// ---------------- single-block bitonic sort (desc) + box decode ----------------
__global__ void sort_decode_k(const uint64_t* __restrict__ cand, const uint32_t* __restrict__ ctl,
                              const float* __restrict__ regs,
                              const int* __restrict__ hp, const int* __restrict__ wp,
                              float* __restrict__ tops_s, float* __restrict__ boxes) {
    __shared__ uint64_t keys[CAND_CAP];
    const int t = threadIdx.x;
    const int M = min((int)ctl[1], CAND_CAP);
    const int N = (M <= 4096) ? 4096 : 8192;
    for (int k = t; k < N; k += 1024) keys[k] = (k < M) ? cand[k] : 0ull;
    __syncthreads();
    for (int size = 2; size <= N; size <<= 1) {
        for (int stride = size >> 1; stride > 0; stride >>= 1) {
            for (int k = t; k < N; k += 1024) {
                const int p = k ^ stride;
                if (p > k) {
                    const uint64_t a = keys[k], bb = keys[p];
                    const bool sw = ((k & size) == 0) ? (a < bb) : (a > bb);
                    if (sw) { keys[k] = bb; keys[p] = a; }
                }
            }
            __syncthreads();
        }
    }
    const int w_in = wp[0], h_in = hp[0];
    const float offx = (float)((w_in - 16) % 16) * 0.5f + 8.0f;
    const float offy = (float)((h_in - 16) % 16) * 0.5f + 8.0f;
    for (int k = t; k < KSEL; k += 1024) {
        const uint64_t key = keys[k];
        float sc = -1.f, x1 = 0.f, y1 = 0.f, x2 = 0.f, y2 = 0.f;
        if (k < M && key != 0ull) {
            const uint32_t idx = 0xFFFFFFFFu - (uint32_t)(key & 0xFFFFFFFFull);
            sc = __uint_as_float((uint32_t)(key >> 32));
            const int a  = (int)(idx / (NH * NW)) % NA;
            const int yy = (int)(idx / NW) % NH;
            const int xx = (int)(idx % NW);
            const float4 r = ((const float4*)regs)[idx];
            const float aw = ANC_W[a], ah = ANC_H[a];
            const float cx = (float)xx * 16.f + offx;
            const float cy = (float)yy * 16.f + offy;
            const float bx = r.x * aw + cx;
            const float by = r.y * ah + cy;
            const float bw = expf(r.z) * aw;
            const float bh = expf(r.w) * ah;
            x1 = bx - bw * 0.5f; y1 = by - bh * 0.5f;
            x2 = bx + bw * 0.5f; y2 = by + bh * 0.5f;
        }
        tops_s[k] = sc;
        ((float4*)boxes)[k] = make_float4(x1, y1, x2, y2);
    }
}

// ---------------- pairwise IoU suppression bitmask ----------------
__global__ void iou_k(const float* __restrict__ boxes, uint64_t* __restrict__ mask) {
    __shared__ float4 jb[64];
    const int t = threadIdx.x;
    const int bi = blockIdx.x, bj = blockIdx.y;
    jb[t] = ((const float4*)boxes)[bj * 64 + t];
    __syncthreads();
    const int i = bi * 64 + t;
    const float4 mb = ((const float4*)boxes)[i];
    const float areai = (mb.z - mb.x) * (mb.w - mb.y);
    uint64_t w = 0;
    for (int jj = 0; jj < 64; ++jj) {
        const float4 ob = jb[jj];
        const int j = bj * 64 + jj;
        const float ix1 = fmaxf(mb.x, ob.x);
        const float iy1 = fmaxf(mb.y, ob.y);
        const float ix2 = fminf(mb.z, ob.z);
        const float iy2 = fminf(mb.w, ob.w);
        const float inter = fmaxf(ix2 - ix1, 0.f) * fmaxf(iy2 - iy1, 0.f);
        const float areaj = (ob.z - ob.x) * (ob.w - ob.y);
        const float iou = inter / (areai + areaj - inter + 1e-9f);
        if (iou > 0.7f && j > i) w |= (1ull << jj);
    }
    mask[(size_t)i * 32 + bj] = w;
}

// ---------------- sequential greedy NMS (single wave, early exit, prefetch) ----------------
__global__ void nms_k(const float* __restrict__ tops_s, const float* __restrict__ boxes,
                      const uint64_t* __restrict__ mask, float* __restrict__ out) {
    __shared__ uint64_t remv[32];
    __shared__ float ssc[KSEL];
    __shared__ int sel[NOUT];
    const int t = threadIdx.x;      // 64 threads = 1 wave
    for (int k = t; k < KSEL; k += 64) ssc[k] = tops_s[k];
    if (t < 32) remv[t] = 0ull;
    uint64_t nextrow = (t < 32) ? mask[t] : 0ull;   // row 0 prefetch
    int cnt = 0;                    // wave-uniform
    for (int i = 0; i < KSEL && cnt < NOUT; ++i) {
        const uint64_t cur = nextrow;
        if (t < 32 && i + 1 < KSEL) nextrow = mask[(size_t)(i + 1) * 32 + t];
        const uint64_t rw = remv[i >> 6];
        const bool sup = (rw >> (i & 63)) & 1ull;
        if (ssc[i] >= THRS && !sup) {
            if (t < 32) remv[t] |= cur;
            if (t == 0) sel[cnt] = i;
            ++cnt;
        }
    }
    for (int k = t; k < NOUT; k += 64) {
        float s = 0.f;
        float4 bb = make_float4(0.f, 0.f, 0.f, 0.f);
        if (k < cnt) { const int i = sel[k]; s = ssc[i]; bb = ((const float4*)boxes)[i]; }
        out[k] = s;
        out[NOUT + k * 4 + 0] = bb.x;
        out[NOUT + k * 4 + 1] = bb.y;
        out[NOUT + k * 4 + 2] = bb.z;
        out[NOUT + k * 4 + 3] = bb.w;
    }
}

extern "C" void kernel_launch(void* const* d_in, const int* in_sizes, int n_in,
                              void* d_out, int out_size, void* d_ws, size_t ws_size,
                              hipStream_t stream) {
    const float* x    = (const float*)d_in[0];
    const float* w1   = (const float*)d_in[1];
    const float* b1   = (const float*)d_in[2];
    const float* wcls = (const float*)d_in[3];
    const float* bcls = (const float*)d_in[4];
    const float* wreg = (const float*)d_in[5];
    const float* breg = (const float*)d_in[6];
    const int*   hp   = (const int*)d_in[7];
    const int*   wp   = (const int*)d_in[8];
    float* out = (float*)d_out;

    char* ws = (char*)d_ws;
    size_t off = 0;
    auto carve = [&](size_t bytes) -> void* {
        void* p = ws + off;
        off = (off + bytes + 255) & ~(size_t)255;
        return p;
    };
    uint4*    wexp2  = (uint4*)carve((size_t)288 * 4 * 512 * 16);      // 9.44 MB
    float*    f      = (float*)carve((size_t)24576 * 512 * 4);         // 50.3 MB
    float*    scores = (float*)carve((size_t)NPIX * 4);
    float*    regs   = (float*)carve((size_t)NPIX * 16);
    uint32_t* hist   = (uint32_t*)carve((size_t)HIST_SIZE * 4);
    uint32_t* ctl    = (uint32_t*)carve(256);
    uint64_t* cand   = (uint64_t*)carve((size_t)CAND_CAP * 8);
    float*    tops_s = (float*)carve((size_t)KSEL * 4);
    float*    boxes  = (float*)carve((size_t)KSEL * 16);
    uint64_t* mask   = (uint64_t*)carve((size_t)KSEL * 32 * 8);
    (void)ws_size; (void)in_sizes; (void)n_in; (void)out_size;

    hipMemsetAsync(hist, 0, (size_t)HIST_SIZE * 4, stream);
    hipMemsetAsync(ctl, 0, 256, stream);

    wexp2_k<<<512, 256, 0, stream>>>(w1, wexp2);
    conv_mfma<<<512, 512, 0, stream>>>(x, wexp2, b1, f);
    head_k<<<192, 256, 0, stream>>>(f, wcls, wreg, bcls, breg, scores, regs);
    hist_k<<<NPIX / 256, 256, 0, stream>>>(scores, hist);
    scan_k<<<1, 1024, 0, stream>>>(hist, ctl);
    collect_k<<<NPIX / 256, 256, 0, stream>>>(scores, ctl, cand);
    sort_decode_k<<<1, 1024, 0, stream>>>(cand, ctl, regs, hp, wp, tops_s, boxes);
    iou_k<<<dim3(KSEL / 64, KSEL / 64), 64, 0, stream>>>(boxes, mask);
    nms_k<<<1, 64, 0, stream>>>(tops_s, boxes, mask, out);
}

// Round 6
// 656.135 us; speedup vs baseline: 1.3965x; 1.0185x over previous
//
#include <hip/hip_runtime.h>
#include <stdint.h>

#define NB 4
#define NC 512
#define NH 64
#define NW 96
#define NA 9
#define NPIX (NB*NA*NH*NW)   // 221184
#define KSEL 2048
#define NOUT 50
#define THRS 0.05f

#define HIST_BASE 0x3D4CCu   // bits(0.05f)>>12
#define HIST_SIZE 9024
#define CAND_CAP 8192

typedef _Float16 half8 __attribute__((ext_vector_type(8)));
typedef float floatx16 __attribute__((ext_vector_type(16)));

__device__ const float ANC_W[9] = {128.f,128.f,256.f,256.f,256.f,512.f,512.f,512.f,1024.f};
__device__ const float ANC_H[9] = {128.f,256.f,128.f,256.f,512.f,256.f,512.f,1024.f,512.f};

// ============ weight expand (coalesced, LDS transpose) ============
// w1[co][ci][3][3] fp32 -> wexp2[(cc*9+kk)][kd(4)][co(512)] half8 (16B units)
// kd = kind*2 + khalf; kind0 = hi, kind1 = lo; values pre-scaled by 1024.
__global__ __launch_bounds__(256) void wexp2_k(const float* __restrict__ w1,
                                               uint4* __restrict__ wexp2) {
    __shared__ __align__(16) _Float16 lbuf[36 * 32 * 8];   // 18432 B
    const int bid = blockIdx.x;
    const int cc = bid >> 4, cog = bid & 15;
    const int t = threadIdx.x;
    const int co_l = t >> 3, j = t & 7;
    const int co = cog * 32 + co_l;
    const float* r0 = w1 + ((size_t)co * 512 + cc * 16 + j) * 9;      // ci = cc*16+j
    const float* r1 = r0 + 8 * 9;                                      // ci = cc*16+8+j
#pragma unroll
    for (int kk = 0; kk < 9; ++kk) {
        const float v0 = r0[kk] * 1024.f;
        const float v1 = r1[kk] * 1024.f;
        const _Float16 h0 = (_Float16)v0, h1 = (_Float16)v1;
        const _Float16 l0 = (_Float16)(v0 - (float)h0);
        const _Float16 l1 = (_Float16)(v1 - (float)h1);
        lbuf[((kk * 4 + 0) * 32 + co_l) * 8 + j] = h0;
        lbuf[((kk * 4 + 1) * 32 + co_l) * 8 + j] = h1;
        lbuf[((kk * 4 + 2) * 32 + co_l) * 8 + j] = l0;
        lbuf[((kk * 4 + 3) * 32 + co_l) * 8 + j] = l1;
    }
    __syncthreads();
    for (int e = t; e < 1152; e += 256) {
        const int co_e = e & 31;
        const int rest = e >> 5;            // kk*4 + kd (0..35)
        const uint4 v = *(const uint4*)&lbuf[(rest * 32 + co_e) * 8];
        wexp2[(((size_t)cc * 9) * 4 + rest) * 512 + cog * 32 + co_e] = v;
    }
}

// ============ conv3x3 via fp16 MFMA, 3-term split, register-B pipeline ============
// grid 512: bid&1 = co-half (256 co; round-robin dispatch -> each XCD sees one
// half => weight working set ~4.7MB ~ its L2). bid>>1 = px-tile (4 rows x 24 cols).
// block 512 thr = 8 waves; wave wq = 32-co slice; 96 px (3 mt) x 32 co per wave.
// B-fragments load DIRECTLY from global (coalesced 16B/lane), 1-chunk register
// prefetch; NO weight LDS; barriers only for x staging: 2 per cc (64 total).
#define XS_BYTES 12480           // 156 slots (6x26 halo) * 80 B
#define CONV_LDS XS_BYTES

__global__ __launch_bounds__(512, 4) void conv_mfma(
    const float* __restrict__ x, const uint4* __restrict__ wexp2,
    const float* __restrict__ b1, float* __restrict__ f)
{
    __shared__ __align__(16) char xs[CONV_LDS];
    const int t = threadIdx.x;
    const int bid = blockIdx.x;
    const int half = bid & 1, pxb = bid >> 1;
    const int b = pxb >> 6, r = pxb & 63, by = r >> 2, bx = r & 3;
    const int y0 = by * 4, x0 = bx * 24;
    const int wq = t >> 6, lane = t & 63;
    const int m32 = lane & 31, khalf = lane >> 5;

    int abase[3];
#pragma unroll
    for (int mt = 0; mt < 3; ++mt) {
        const int px = mt * 32 + m32;
        const int yl = px / 24, xl = px - yl * 24;
        abase[mt] = (yl * 26 + xl) * 80 + khalf * 16;
    }

    floatx16 acc[3];
#pragma unroll
    for (int mt = 0; mt < 3; ++mt)
#pragma unroll
        for (int i = 0; i < 16; ++i) acc[mt][i] = 0.f;

    // per-lane B source: wexp2[(q*4 + kind*2 + khalf)*512 + half*256 + wq*32 + m32]
    const uint4* wsrc = wexp2 + (size_t)khalf * 512 + (half * 256 + wq * 32 + m32);

    const float* xb = x + (size_t)b * NC * (NH * NW);
    auto stage_x = [&](int cc) {
        const float* xc = xb + (size_t)cc * 16 * (NH * NW);
        for (int it = t; it < 312; it += 512) {
            const int kh = (it >= 156) ? 1 : 0;
            const int slot = it - kh * 156;
            const int ya = slot / 26, xa = slot - ya * 26;
            const int gy = y0 - 1 + ya, gx = x0 - 1 + xa;
            const bool ok = (gy >= 0 && gy < NH && gx >= 0 && gx < NW);
            const int off = ok ? (kh * 8 * 6144 + gy * 96 + gx) : 0;
            union { _Float16 h[8]; uint4 u; } hi, lo;
#pragma unroll
            for (int j = 0; j < 8; ++j) {
                const float v = (ok ? xc[off + j * 6144] : 0.f) * 1024.f;
                const _Float16 hh = (_Float16)v;
                hi.h[j] = hh;
                lo.h[j] = (_Float16)(v - (float)hh);
            }
            *(uint4*)(xs + slot * 80 + kh * 16) = hi.u;
            *(uint4*)(xs + slot * 80 + 32 + kh * 16) = lo.u;
        }
    };

    uint4 bch, bcl, bnh, bnl;
    bch = wsrc[0];               // chunk 0: hi (kind0)
    bcl = wsrc[1024];            // chunk 0: lo (kind1)

    int cc = 0, kk = 0;
    for (int q = 0; q < 288; ++q) {
        if (kk == 0) {
            __syncthreads();                 // prev-cc xs readers done
            stage_x(cc);
            __syncthreads();                 // xs visible
        }
        if (q < 287) {                       // prefetch next chunk's B (in flight
            const size_t nb = (size_t)(q + 1) * 2048;   //  across the compute)
            bnh = wsrc[nb];
            bnl = wsrc[nb + 1024];
        }
        // ---- compute chunk q: 9 MFMA (3 steps x 3 mt) ----
        {
            const int ky = kk / 3, kx = kk - ky * 3;
            const char* xcur = xs + (ky * 26 + kx) * 80;
            half8 axh[3], axl[3];
#pragma unroll
            for (int mt = 0; mt < 3; ++mt) {
                axh[mt] = *(const half8*)(xcur + abase[mt]);
                axl[mt] = *(const half8*)(xcur + abase[mt] + 32);
            }
            const half8 bwh = __builtin_bit_cast(half8, bch);
            const half8 bwl = __builtin_bit_cast(half8, bcl);
#pragma unroll
            for (int mt = 0; mt < 3; ++mt)
                acc[mt] = __builtin_amdgcn_mfma_f32_32x32x16_f16(
                    axh[mt], bwh, acc[mt], 0, 0, 0);
#pragma unroll
            for (int mt = 0; mt < 3; ++mt)
                acc[mt] = __builtin_amdgcn_mfma_f32_32x32x16_f16(
                    axh[mt], bwl, acc[mt], 0, 0, 0);
#pragma unroll
            for (int mt = 0; mt < 3; ++mt)
                acc[mt] = __builtin_amdgcn_mfma_f32_32x32x16_f16(
                    axl[mt], bwh, acc[mt], 0, 0, 0);
        }
        bch = bnh; bcl = bnl;
        if (++kk == 9) { kk = 0; ++cc; }
    }

    // epilogue: descale 2^-20, + bias, store f[px][co]  (R2/R4-clean write geometry)
    const float inv = 1.0f / 1048576.0f;
    const int co = half * 256 + wq * 32 + m32;
    const float bias = b1[co];
#pragma unroll
    for (int mt = 0; mt < 3; ++mt) {
#pragma unroll
        for (int reg = 0; reg < 16; ++reg) {
            const int row = (reg & 3) + 8 * (reg >> 2) + 4 * khalf;
            const int pxl = mt * 32 + row;
            const int yl = pxl / 24, xl = pxl - yl * 24;
            const size_t gpx = (size_t)(b * 64 + y0 + yl) * 96 + (x0 + xl);
            f[gpx * 512 + co] = acc[mt][reg] * inv + bias;
        }
    }
}

// ============ fused heads + softmax: f[24576][512] -> scores, regs ============
// grid 192, block 256: px_l = t&127 (128 px/block), oh = t>>7 (27 oc each)
__global__ __launch_bounds__(256) void head_k(
    const float* __restrict__ f, const float* __restrict__ wcls,
    const float* __restrict__ wreg, const float* __restrict__ bcls,
    const float* __restrict__ breg, float* __restrict__ scores,
    float* __restrict__ regs)
{
    __shared__ __align__(16) float smem[6912 + 128 * 57];   // 56.0 KB
    float* wls = smem;                 // [54][128]
    float* lt  = smem + 6912;          // [128][57]
    const int t = threadIdx.x;
    const int px0 = blockIdx.x * 128;
    const int px_l = t & 127, oh = t >> 7;
    float acc27[27];
#pragma unroll
    for (int k = 0; k < 27; ++k) acc27[k] = 0.f;

    for (int qd = 0; qd < 4; ++qd) {
        __syncthreads();
        for (int e = t; e < 6912; e += 256) {
            const int oc = e >> 7, c = e & 127;
            wls[e] = (oc < 18) ? wcls[oc * 512 + qd * 128 + c]
                               : wreg[(oc - 18) * 512 + qd * 128 + c];
        }
        __syncthreads();
        const float4* fp = (const float4*)(f + (size_t)(px0 + px_l) * 512 + qd * 128);
        const float4* wp4 = (const float4*)wls;
#pragma unroll 4
        for (int c4 = 0; c4 < 32; ++c4) {
            const float4 fv = fp[c4];
#pragma unroll
            for (int k = 0; k < 27; ++k) {
                const float4 wv = wp4[(oh * 27 + k) * 32 + c4];
                acc27[k] += fv.x * wv.x + fv.y * wv.y + fv.z * wv.z + fv.w * wv.w;
            }
        }
    }
    __syncthreads();
#pragma unroll
    for (int k = 0; k < 27; ++k) lt[px_l * 57 + oh * 27 + k] = acc27[k];
    __syncthreads();

    if (t < 128) {
        const int px = px0 + t;
        const float* row = lt + t * 57;
        float cl[18];
        float m = -1e30f;
#pragma unroll
        for (int oc = 0; oc < 18; ++oc) {
            cl[oc] = row[oc] + bcls[oc];
            m = fmaxf(m, cl[oc]);
        }
        float sum = 0.f;
#pragma unroll
        for (int oc = 0; oc < 18; ++oc) { cl[oc] = expf(cl[oc] - m); sum += cl[oc]; }
        const float inv = 1.f / sum;
        const int b = px / 6144;
        const int yx = px - b * 6144;
#pragma unroll
        for (int a = 0; a < 9; ++a) {
            const int idx = b * 55296 + a * 6144 + yx;
            scores[idx] = cl[2 * a + 1] * inv;
            float4 rv;
            rv.x = row[18 + a * 4 + 0] + breg[a * 4 + 0];
            rv.y = row[18 + a * 4 + 1] + breg[a * 4 + 1];
            rv.z = row[18 + a * 4 + 2] + breg[a * 4 + 2];
            rv.w = row[18 + a * 4 + 3] + breg[a * 4 + 3];
            ((float4*)regs)[idx] = rv;
        }
    }
}

// ---------------- histogram (LDS-privatized: scores cluster near 1/18) ----------------
// grid 216 x 256 thr, 4 consecutive scores (float4) per thread.
__global__ __launch_bounds__(256) void hist_k(const float* __restrict__ scores,
                                              uint32_t* __restrict__ hist) {
    __shared__ uint32_t lh[HIST_SIZE];     // 36 KB
    const int t = threadIdx.x;
    for (int e = t; e < HIST_SIZE; e += 256) lh[e] = 0u;
    __syncthreads();
    const float4 sv = ((const float4*)scores)[blockIdx.x * 256 + t];
    const float s4[4] = {sv.x, sv.y, sv.z, sv.w};
#pragma unroll
    for (int j = 0; j < 4; ++j) {
        const float s = s4[j];
        if (s >= THRS) {
            int bkt = (int)(__float_as_uint(s) >> 12) - (int)HIST_BASE;
            bkt = min(max(bkt, 0), HIST_SIZE - 1);
            atomicAdd(&lh[bkt], 1u);
        }
    }
    __syncthreads();
    for (int e = t; e < HIST_SIZE; e += 256) {
        const uint32_t v = lh[e];
        if (v) atomicAdd(&hist[e], v);
    }
}

// ---------------- suffix scan -> cutoff bucket ----------------
__global__ void scan_k(const uint32_t* __restrict__ hist, uint32_t* __restrict__ ctl) {
    __shared__ uint32_t ssum[1024];
    const int t = threadIdx.x;
    uint32_t s = 0;
#pragma unroll
    for (int u = 0; u < 9; ++u) {
        const int bkt = t * 9 + u;
        if (bkt < HIST_SIZE) s += hist[bkt];
    }
    const uint32_t mysum = s;
    ssum[t] = s;
    __syncthreads();
    for (int off = 1; off < 1024; off <<= 1) {
        uint32_t v = (t + off < 1024) ? ssum[t + off] : 0u;
        __syncthreads();
        ssum[t] += v;
        __syncthreads();
    }
    const uint32_t total = ssum[0];
    const uint32_t above = (t < 1023) ? ssum[t + 1] : 0u;
    if (total < KSEL) {
        if (t == 0) ctl[0] = HIST_BASE;
    } else if (above < KSEL && above + mysum >= KSEL) {
        uint32_t run = above;
        for (int u = 8; u >= 0; --u) {
            const int bkt = t * 9 + u;
            if (bkt >= HIST_SIZE) continue;
            run += hist[bkt];
            if (run >= KSEL) { ctl[0] = HIST_BASE + (uint32_t)bkt; break; }
        }
    }
}

// ---------------- compact candidates above cutoff ----------------
__global__ void collect_k(const float* __restrict__ scores, uint32_t* __restrict__ ctl,
                          uint64_t* __restrict__ cand) {
    const int i = blockIdx.x * 256 + threadIdx.x;
    const float s = scores[i];
    if (s >= THRS) {
        const uint32_t bits = __float_as_uint(s);
        if ((bits >> 12) >= ctl[0]) {
            const uint32_t pos = atomicAdd(&ctl[1], 1u);
            if (pos < CAND_CAP)
                cand[pos] = ((uint64_t)bits << 32) | (uint64_t)(0xFFFFFFFFu - (uint32_t)i);
        }
    }
}

// ---------------- single-block bitonic sort (desc) + box decode ----------------
__global__ void sort_decode_k(const uint64_t* __restrict__ cand, const uint32_t* __restrict__ ctl,
                              const float* __restrict__ regs,
                              const int* __restrict__ hp, const int* __restrict__ wp,
                              float* __restrict__ tops_s, float* __restrict__ boxes) {
    __shared__ uint64_t keys[CAND_CAP];
    const int t = threadIdx.x;
    const int M = min((int)ctl[1], CAND_CAP);
    const int N = (M <= 4096) ? 4096 : 8192;
    for (int k = t; k < N; k += 1024) keys[k] = (k < M) ? cand[k] : 0ull;
    __syncthreads();
    for (int size = 2; size <= N; size <<= 1) {
        for (int stride = size >> 1; stride > 0; stride >>= 1) {
            for (int k = t; k < N; k += 1024) {
                const int p = k ^ stride;
                if (p > k) {
                    const uint64_t a = keys[k], bb = keys[p];
                    const bool sw = ((k & size) == 0) ? (a < bb) : (a > bb);
                    if (sw) { keys[k] = bb; keys[p] = a; }
                }
            }
            __syncthreads();
        }
    }
    const int w_in = wp[0], h_in = hp[0];
    const float offx = (float)((w_in - 16) % 16) * 0.5f + 8.0f;
    const float offy = (float)((h_in - 16) % 16) * 0.5f + 8.0f;
    for (int k = t; k < KSEL; k += 1024) {
        const uint64_t key = keys[k];
        float sc = -1.f, x1 = 0.f, y1 = 0.f, x2 = 0.f, y2 = 0.f;
        if (k < M && key != 0ull) {
            const uint32_t idx = 0xFFFFFFFFu - (uint32_t)(key & 0xFFFFFFFFull);
            sc = __uint_as_float((uint32_t)(key >> 32));
            const int a  = (int)(idx / (NH * NW)) % NA;
            const int yy = (int)(idx / NW) % NH;
            const int xx = (int)(idx % NW);
            const float4 r = ((const float4*)regs)[idx];
            const float aw = ANC_W[a], ah = ANC_H[a];
            const float cx = (float)xx * 16.f + offx;
            const float cy = (float)yy * 16.f + offy;
            const float bx = r.x * aw + cx;
            const float by = r.y * ah + cy;
            const float bw = expf(r.z) * aw;
            const float bh = expf(r.w) * ah;
            x1 = bx - bw * 0.5f; y1 = by - bh * 0.5f;
            x2 = bx + bw * 0.5f; y2 = by + bh * 0.5f;
        }
        tops_s[k] = sc;
        ((float4*)boxes)[k] = make_float4(x1, y1, x2, y2);
    }
}

// ---------------- pairwise IoU suppression bitmask ----------------
__global__ void iou_k(const float* __restrict__ boxes, uint64_t* __restrict__ mask) {
    __shared__ float4 jb[64];
    const int t = threadIdx.x;
    const int bi = blockIdx.x, bj = blockIdx.y;
    jb[t] = ((const float4*)boxes)[bj * 64 + t];
    __syncthreads();
    const int i = bi * 64 + t;
    const float4 mb = ((const float4*)boxes)[i];
    const float areai = (mb.z - mb.x) * (mb.w - mb.y);
    uint64_t w = 0;
    for (int jj = 0; jj < 64; ++jj) {
        const float4 ob = jb[jj];
        const int j = bj * 64 + jj;
        const float ix1 = fmaxf(mb.x, ob.x);
        const float iy1 = fmaxf(mb.y, ob.y);
        const float ix2 = fminf(mb.z, ob.z);
        const float iy2 = fminf(mb.w, ob.w);
        const float inter = fmaxf(ix2 - ix1, 0.f) * fmaxf(iy2 - iy1, 0.f);
        const float areaj = (ob.z - ob.x) * (ob.w - ob.y);
        const float iou = inter / (areai + areaj - inter + 1e-9f);
        if (iou > 0.7f && j > i) w |= (1ull << jj);
    }
    mask[(size_t)i * 32 + bj] = w;
}

// ---------------- sequential greedy NMS (single wave, early exit, prefetch) ----------------
__global__ void nms_k(const float* __restrict__ tops_s, const float* __restrict__ boxes,
                      const uint64_t* __restrict__ mask, float* __restrict__ out) {
    __shared__ uint64_t remv[32];
    __shared__ float ssc[KSEL];
    __shared__ int sel[NOUT];
    const int t = threadIdx.x;      // 64 threads = 1 wave
    for (int k = t; k < KSEL; k += 64) ssc[k] = tops_s[k];
    if (t < 32) remv[t] = 0ull;
    uint64_t nextrow = (t < 32) ? mask[t] : 0ull;   // row 0 prefetch
    int cnt = 0;                    // wave-uniform
    for (int i = 0; i < KSEL && cnt < NOUT; ++i) {
        const uint64_t cur = nextrow;
        if (t < 32 && i + 1 < KSEL) nextrow = mask[(size_t)(i + 1) * 32 + t];
        const uint64_t rw = remv[i >> 6];
        const bool sup = (rw >> (i & 63)) & 1ull;
        if (ssc[i] >= THRS && !sup) {
            if (t < 32) remv[t] |= cur;
            if (t == 0) sel[cnt] = i;
            ++cnt;
        }
    }
    for (int k = t; k < NOUT; k += 64) {
        float s = 0.f;
        float4 bb = make_float4(0.f, 0.f, 0.f, 0.f);
        if (k < cnt) { const int i = sel[k]; s = ssc[i]; bb = ((const float4*)boxes)[i]; }
        out[k] = s;
        out[NOUT + k * 4 + 0] = bb.x;
        out[NOUT + k * 4 + 1] = bb.y;
        out[NOUT + k * 4 + 2] = bb.z;
        out[NOUT + k * 4 + 3] = bb.w;
    }
}

extern "C" void kernel_launch(void* const* d_in, const int* in_sizes, int n_in,
                              void* d_out, int out_size, void* d_ws, size_t ws_size,
                              hipStream_t stream) {
    const float* x    = (const float*)d_in[0];
    const float* w1   = (const float*)d_in[1];
    const float* b1   = (const float*)d_in[2];
    const float* wcls = (const float*)d_in[3];
    const float* bcls = (const float*)d_in[4];
    const float* wreg = (const float*)d_in[5];
    const float* breg = (const float*)d_in[6];
    const int*   hp   = (const int*)d_in[7];
    const int*   wp   = (const int*)d_in[8];
    float* out = (float*)d_out;

    char* ws = (char*)d_ws;
    size_t off = 0;
    auto carve = [&](size_t bytes) -> void* {
        void* p = ws + off;
        off = (off + bytes + 255) & ~(size_t)255;
        return p;
    };
    uint4*    wexp2  = (uint4*)carve((size_t)288 * 4 * 512 * 16);      // 9.44 MB
    float*    f      = (float*)carve((size_t)24576 * 512 * 4);         // 50.3 MB
    float*    scores = (float*)carve((size_t)NPIX * 4);
    float*    regs   = (float*)carve((size_t)NPIX * 16);
    uint32_t* hist   = (uint32_t*)carve((size_t)HIST_SIZE * 4);
    uint32_t* ctl    = (uint32_t*)carve(256);
    uint64_t* cand   = (uint64_t*)carve((size_t)CAND_CAP * 8);
    float*    tops_s = (float*)carve((size_t)KSEL * 4);
    float*    boxes  = (float*)carve((size_t)KSEL * 16);
    uint64_t* mask   = (uint64_t*)carve((size_t)KSEL * 32 * 8);
    (void)ws_size; (void)in_sizes; (void)n_in; (void)out_size;

    hipMemsetAsync(hist, 0, (size_t)HIST_SIZE * 4, stream);
    hipMemsetAsync(ctl, 0, 256, stream);

    wexp2_k<<<512, 256, 0, stream>>>(w1, wexp2);
    conv_mfma<<<512, 512, 0, stream>>>(x, wexp2, b1, f);
    head_k<<<192, 256, 0, stream>>>(f, wcls, wreg, bcls, breg, scores, regs);
    hist_k<<<216, 256, 0, stream>>>(scores, hist);
    scan_k<<<1, 1024, 0, stream>>>(hist, ctl);
    collect_k<<<NPIX / 256, 256, 0, stream>>>(scores, ctl, cand);
    sort_decode_k<<<1, 1024, 0, stream>>>(cand, ctl, regs, hp, wp, tops_s, boxes);
    iou_k<<<dim3(KSEL / 64, KSEL / 64), 64, 0, stream>>>(boxes, mask);
    nms_k<<<1, 64, 0, stream>>>(tops_s, boxes, mask, out);
}